// Round 2
// baseline (1233.559 us; speedup 1.0000x reference)
//
#include <hip/hip_runtime.h>
#include <hip/hip_bf16.h>

// SwiGLU FFN, fp32 in/out:  out = clamp(silu(x@w1t) * (x@w3t), ±65504) @ w2t
// x[8192,3072] f32, w13[16384,3072] f32 (rows 0..8191 = w3 -> x3, 8192.. = w1 -> x1),
// w2[3072,8192] f32, out[8192,3072] f32.
// Compute: cast to bf16, MFMA 16x16x32_bf16, fp32 accum, fp32 store.
// ws-adaptive: T1 (ws >= 335.5MB): convert x/w13/w2 to bf16 once + full g buffer,
//              gload_lds(16B) staging.  T2: fp32-source reg-staged GEMMs, g chunked.
// LDS tile layout (both paths): LDS[row][slot] = SRC[row][slot ^ (row&7)] (8-elem slots)
// -> bank-conflict-free swizzled ds_read_b128, linear gload_lds dest (rule #21).

typedef __attribute__((ext_vector_type(8))) __bf16 bf16x8;
typedef __attribute__((ext_vector_type(4))) float f32x4;

#define GLD_LDS16(gptr, lptr)                                                        \
  __builtin_amdgcn_global_load_lds(                                                  \
      (const __attribute__((address_space(1))) void*)(gptr),                         \
      (__attribute__((address_space(3))) void*)(lptr), 16, 0, 0)

__device__ __forceinline__ __bf16 bfr(float f) {  // RNE fp32->bf16
  unsigned int u = __builtin_bit_cast(unsigned int, f);
  unsigned short r = (unsigned short)((u + 0x7FFFu + ((u >> 16) & 1u)) >> 16);
  return __builtin_bit_cast(__bf16, r);
}

// ---------------- fp32 -> bf16 conversion (T1 pre-pass) ----------------
__global__ __launch_bounds__(256)
void k_cvt(const float* __restrict__ src, unsigned short* __restrict__ dst, long n) {
  long i = ((long)blockIdx.x * 256 + threadIdx.x) * 8;
  const long stride = (long)gridDim.x * 256 * 8;
  for (; i < n; i += stride) {
    float4 f0 = *(const float4*)(src + i);
    float4 f1 = *(const float4*)(src + i + 4);
    bf16x8 o;
    o[0] = bfr(f0.x); o[1] = bfr(f0.y); o[2] = bfr(f0.z); o[3] = bfr(f0.w);
    o[4] = bfr(f1.x); o[5] = bfr(f1.y); o[6] = bfr(f1.z); o[7] = bfr(f1.w);
    *(bf16x8*)(dst + i) = o;
  }
}

// ---------------- staging helpers ----------------
// Stage a 128x64 bf16 tile into LDS with read-swizzle layout.
// fp32 source: linear global read, swizzled ds_write.
__device__ __forceinline__ void stage_f32_tile(const float* __restrict__ src, int ld,
                                               unsigned short* __restrict__ lds, int t) {
  const int srow = t >> 3;   // 0..31
  const int sg = t & 7;      // linear global slot
#pragma unroll
  for (int c = 0; c < 4; ++c) {
    const int row = c * 32 + srow;
    const float* p = src + (size_t)row * ld + sg * 8;
    float4 f0 = *(const float4*)p;
    float4 f1 = *(const float4*)(p + 4);
    bf16x8 o;
    o[0] = bfr(f0.x); o[1] = bfr(f0.y); o[2] = bfr(f0.z); o[3] = bfr(f0.w);
    o[4] = bfr(f1.x); o[5] = bfr(f1.y); o[6] = bfr(f1.z); o[7] = bfr(f1.w);
    *(bf16x8*)(lds + row * 64 + ((sg ^ (row & 7)) * 8)) = o;
  }
}

// ---------------- Kernel 1 FAST: fused gate/up GEMM + SiLU*mul (bf16 sources) ----
__global__ __launch_bounds__(256, 2)
void k_gateup_f(const unsigned short* __restrict__ X,
                const unsigned short* __restrict__ W13,
                __hip_bfloat16* __restrict__ G)
{
  constexpr int K = 3072;
  constexpr int LDG = 8192;
  __shared__ unsigned short As[128 * 64];
  __shared__ unsigned short B3s[128 * 64];
  __shared__ unsigned short B1s[128 * 64];

  const int t = threadIdx.x;
  const int lane = t & 63;
  const int wid = t >> 6;
  const int wm = wid >> 1, wn = wid & 1;
  const int l15 = lane & 15, lhi = lane >> 4;
  const int nb = blockIdx.x, mb = blockIdx.y;

  const int srow = t >> 3;
  const int scol = ((t & 7) ^ (srow & 7)) * 8;  // pre-swizzled global slot
  const unsigned short* xa  = X   + (size_t)(mb * 128 + srow) * K + scol;
  const unsigned short* wb3 = W13 + (size_t)(nb * 128 + srow) * K + scol;
  const unsigned short* wb1 = W13 + (size_t)(8192 + nb * 128 + srow) * K + scol;
  unsigned short* lA  = As  + t * 8;
  unsigned short* lB3 = B3s + t * 8;
  unsigned short* lB1 = B1s + t * 8;

  f32x4 acc3[4][4], acc1[4][4];
#pragma unroll
  for (int i = 0; i < 4; ++i)
#pragma unroll
    for (int j = 0; j < 4; ++j) {
      acc3[i][j] = (f32x4){0.f, 0.f, 0.f, 0.f};
      acc1[i][j] = (f32x4){0.f, 0.f, 0.f, 0.f};
    }
  const int sw = l15 & 7;

  for (int kt = 0; kt < K; kt += 64) {
    __syncthreads();
#pragma unroll
    for (int c = 0; c < 4; ++c) {
      GLD_LDS16(xa  + (size_t)(c * 32) * K + kt, lA  + c * 2048);
      GLD_LDS16(wb3 + (size_t)(c * 32) * K + kt, lB3 + c * 2048);
      GLD_LDS16(wb1 + (size_t)(c * 32) * K + kt, lB1 + c * 2048);
    }
    __syncthreads();
#pragma unroll
    for (int kk = 0; kk < 2; ++kk) {
      const int slot = (kk * 4 + lhi) ^ sw;
      bf16x8 av[4], bv3[4], bv1[4];
#pragma unroll
      for (int i = 0; i < 4; ++i) {
        av[i]  = *(const bf16x8*)(As  + (wm * 64 + i * 16 + l15) * 64 + slot * 8);
        bv3[i] = *(const bf16x8*)(B3s + (wn * 64 + i * 16 + l15) * 64 + slot * 8);
        bv1[i] = *(const bf16x8*)(B1s + (wn * 64 + i * 16 + l15) * 64 + slot * 8);
      }
#pragma unroll
      for (int i = 0; i < 4; ++i)
#pragma unroll
        for (int j = 0; j < 4; ++j) {
          acc3[i][j] = __builtin_amdgcn_mfma_f32_16x16x32_bf16(av[i], bv3[j], acc3[i][j], 0, 0, 0);
          acc1[i][j] = __builtin_amdgcn_mfma_f32_16x16x32_bf16(av[i], bv1[j], acc1[i][j], 0, 0, 0);
        }
    }
  }

  const int gr0 = mb * 128 + wm * 64;
  const int gc0 = nb * 128 + wn * 64;
#pragma unroll
  for (int i = 0; i < 4; ++i)
#pragma unroll
    for (int j = 0; j < 4; ++j)
#pragma unroll
      for (int r = 0; r < 4; ++r) {
        float h3 = acc3[i][j][r];
        float h1 = acc1[i][j][r];
        float s  = h1 / (1.f + __expf(-h1));
        float g  = fminf(fmaxf(s * h3, -65504.f), 65504.f);
        G[(size_t)(gr0 + i * 16 + lhi * 4 + r) * LDG + (gc0 + j * 16 + l15)] =
            __float2bfloat16(g);
      }
}

// ---------------- Kernel 1 SAFE: fp32 sources, reg-staged ----------------
__global__ __launch_bounds__(256, 2)
void k_gateup_s(const float* __restrict__ X,
                const float* __restrict__ W13,
                __hip_bfloat16* __restrict__ G)
{
  constexpr int K = 3072;
  constexpr int LDG = 8192;
  __shared__ unsigned short As[128 * 64];
  __shared__ unsigned short B3s[128 * 64];
  __shared__ unsigned short B1s[128 * 64];

  const int t = threadIdx.x;
  const int lane = t & 63;
  const int wid = t >> 6;
  const int wm = wid >> 1, wn = wid & 1;
  const int l15 = lane & 15, lhi = lane >> 4;
  const int nb = blockIdx.x, mb = blockIdx.y;

  const float* xa  = X   + (size_t)(mb * 128) * K;
  const float* wb3 = W13 + (size_t)(nb * 128) * K;
  const float* wb1 = W13 + (size_t)(8192 + nb * 128) * K;

  f32x4 acc3[4][4], acc1[4][4];
#pragma unroll
  for (int i = 0; i < 4; ++i)
#pragma unroll
    for (int j = 0; j < 4; ++j) {
      acc3[i][j] = (f32x4){0.f, 0.f, 0.f, 0.f};
      acc1[i][j] = (f32x4){0.f, 0.f, 0.f, 0.f};
    }
  const int sw = l15 & 7;

  for (int kt = 0; kt < K; kt += 64) {
    __syncthreads();
    stage_f32_tile(xa  + kt, K, As,  t);
    stage_f32_tile(wb3 + kt, K, B3s, t);
    stage_f32_tile(wb1 + kt, K, B1s, t);
    __syncthreads();
#pragma unroll
    for (int kk = 0; kk < 2; ++kk) {
      const int slot = (kk * 4 + lhi) ^ sw;
      bf16x8 av[4], bv3[4], bv1[4];
#pragma unroll
      for (int i = 0; i < 4; ++i) {
        av[i]  = *(const bf16x8*)(As  + (wm * 64 + i * 16 + l15) * 64 + slot * 8);
        bv3[i] = *(const bf16x8*)(B3s + (wn * 64 + i * 16 + l15) * 64 + slot * 8);
        bv1[i] = *(const bf16x8*)(B1s + (wn * 64 + i * 16 + l15) * 64 + slot * 8);
      }
#pragma unroll
      for (int i = 0; i < 4; ++i)
#pragma unroll
        for (int j = 0; j < 4; ++j) {
          acc3[i][j] = __builtin_amdgcn_mfma_f32_16x16x32_bf16(av[i], bv3[j], acc3[i][j], 0, 0, 0);
          acc1[i][j] = __builtin_amdgcn_mfma_f32_16x16x32_bf16(av[i], bv1[j], acc1[i][j], 0, 0, 0);
        }
    }
  }

  const int gr0 = mb * 128 + wm * 64;
  const int gc0 = nb * 128 + wn * 64;
#pragma unroll
  for (int i = 0; i < 4; ++i)
#pragma unroll
    for (int j = 0; j < 4; ++j)
#pragma unroll
      for (int r = 0; r < 4; ++r) {
        float h3 = acc3[i][j][r];
        float h1 = acc1[i][j][r];
        float s  = h1 / (1.f + __expf(-h1));
        float g  = fminf(fmaxf(s * h3, -65504.f), 65504.f);
        G[(size_t)(gr0 + i * 16 + lhi * 4 + r) * LDG + (gc0 + j * 16 + l15)] =
            __float2bfloat16(g);
      }
}

// ---------------- Kernel 2 FAST: down projection (bf16 sources) ----------------
__global__ __launch_bounds__(256, 2)
void k_down_f(const unsigned short* __restrict__ G,
              const unsigned short* __restrict__ W2,
              float* __restrict__ Out)
{
  constexpr int K = 8192;
  constexpr int LDO = 3072;
  __shared__ unsigned short As[128 * 64];
  __shared__ unsigned short Bs[128 * 64];

  const int t = threadIdx.x;
  const int lane = t & 63;
  const int wid = t >> 6;
  const int wm = wid >> 1, wn = wid & 1;
  const int l15 = lane & 15, lhi = lane >> 4;
  const int nb = blockIdx.x, mb = blockIdx.y;

  const int srow = t >> 3;
  const int scol = ((t & 7) ^ (srow & 7)) * 8;
  const unsigned short* ga = G  + (size_t)(mb * 128 + srow) * K + scol;
  const unsigned short* wb = W2 + (size_t)(nb * 128 + srow) * K + scol;
  unsigned short* lA = As + t * 8;
  unsigned short* lB = Bs + t * 8;

  f32x4 acc[4][4];
#pragma unroll
  for (int i = 0; i < 4; ++i)
#pragma unroll
    for (int j = 0; j < 4; ++j)
      acc[i][j] = (f32x4){0.f, 0.f, 0.f, 0.f};
  const int sw = l15 & 7;

  for (int kt = 0; kt < K; kt += 64) {
    __syncthreads();
#pragma unroll
    for (int c = 0; c < 4; ++c) {
      GLD_LDS16(ga + (size_t)(c * 32) * K + kt, lA + c * 2048);
      GLD_LDS16(wb + (size_t)(c * 32) * K + kt, lB + c * 2048);
    }
    __syncthreads();
#pragma unroll
    for (int kk = 0; kk < 2; ++kk) {
      const int slot = (kk * 4 + lhi) ^ sw;
      bf16x8 av[4], bv[4];
#pragma unroll
      for (int i = 0; i < 4; ++i) {
        av[i] = *(const bf16x8*)(As + (wm * 64 + i * 16 + l15) * 64 + slot * 8);
        bv[i] = *(const bf16x8*)(Bs + (wn * 64 + i * 16 + l15) * 64 + slot * 8);
      }
#pragma unroll
      for (int i = 0; i < 4; ++i)
#pragma unroll
        for (int j = 0; j < 4; ++j)
          acc[i][j] = __builtin_amdgcn_mfma_f32_16x16x32_bf16(av[i], bv[j], acc[i][j], 0, 0, 0);
    }
  }

  const int r0 = mb * 128 + wm * 64;
  const int c0 = nb * 128 + wn * 64;
#pragma unroll
  for (int i = 0; i < 4; ++i)
#pragma unroll
    for (int j = 0; j < 4; ++j)
#pragma unroll
      for (int r = 0; r < 4; ++r)
        Out[(size_t)(r0 + i * 16 + lhi * 4 + r) * LDO + (c0 + j * 16 + l15)] =
            acc[i][j][r];
}

// ---------------- Kernel 2 SAFE: g bf16 (gload_lds) + w2 fp32 (reg-staged) ------
__global__ __launch_bounds__(256, 2)
void k_down_s(const unsigned short* __restrict__ G,
              const float* __restrict__ W2,
              float* __restrict__ Out)
{
  constexpr int K = 8192;
  constexpr int LDO = 3072;
  __shared__ unsigned short As[128 * 64];
  __shared__ unsigned short Bs[128 * 64];

  const int t = threadIdx.x;
  const int lane = t & 63;
  const int wid = t >> 6;
  const int wm = wid >> 1, wn = wid & 1;
  const int l15 = lane & 15, lhi = lane >> 4;
  const int nb = blockIdx.x, mb = blockIdx.y;

  const int srow = t >> 3;
  const int scol = ((t & 7) ^ (srow & 7)) * 8;
  const unsigned short* ga = G + (size_t)(mb * 128 + srow) * K + scol;
  const float* wb = W2 + (size_t)(nb * 128) * K;
  unsigned short* lA = As + t * 8;

  f32x4 acc[4][4];
#pragma unroll
  for (int i = 0; i < 4; ++i)
#pragma unroll
    for (int j = 0; j < 4; ++j)
      acc[i][j] = (f32x4){0.f, 0.f, 0.f, 0.f};
  const int sw = l15 & 7;

  for (int kt = 0; kt < K; kt += 64) {
    __syncthreads();
#pragma unroll
    for (int c = 0; c < 4; ++c)
      GLD_LDS16(ga + (size_t)(c * 32) * K + kt, lA + c * 2048);
    stage_f32_tile(wb + kt, K, Bs, t);
    __syncthreads();
#pragma unroll
    for (int kk = 0; kk < 2; ++kk) {
      const int slot = (kk * 4 + lhi) ^ sw;
      bf16x8 av[4], bv[4];
#pragma unroll
      for (int i = 0; i < 4; ++i) {
        av[i] = *(const bf16x8*)(As + (wm * 64 + i * 16 + l15) * 64 + slot * 8);
        bv[i] = *(const bf16x8*)(Bs + (wn * 64 + i * 16 + l15) * 64 + slot * 8);
      }
#pragma unroll
      for (int i = 0; i < 4; ++i)
#pragma unroll
        for (int j = 0; j < 4; ++j)
          acc[i][j] = __builtin_amdgcn_mfma_f32_16x16x32_bf16(av[i], bv[j], acc[i][j], 0, 0, 0);
    }
  }

  const int r0 = mb * 128 + wm * 64;
  const int c0 = nb * 128 + wn * 64;
#pragma unroll
  for (int i = 0; i < 4; ++i)
#pragma unroll
    for (int j = 0; j < 4; ++j)
#pragma unroll
      for (int r = 0; r < 4; ++r)
        Out[(size_t)(r0 + i * 16 + lhi * 4 + r) * LDO + (c0 + j * 16 + l15)] =
            acc[i][j][r];
}

extern "C" void kernel_launch(void* const* d_in, const int* in_sizes, int n_in,
                              void* d_out, int out_size, void* d_ws, size_t ws_size,
                              hipStream_t stream) {
  const float* x   = (const float*)d_in[0];   // [2,4096,3072] f32
  const float* w13 = (const float*)d_in[1];   // [16384,3072] f32
  const float* w2  = (const float*)d_in[2];   // [3072,8192] f32
  float* out = (float*)d_out;                 // [2,4096,3072] f32

  const long NX = 25165824L, NW13 = 50331648L, NW2 = 25165824L;
  const size_t XB = 50331648, W13B = 100663296, W2B = 50331648, GB = 134217728;

  if (ws_size >= XB + W13B + W2B + GB) {
    // ---- T1: convert everything to bf16 once, fast gload_lds GEMMs ----
    unsigned short* xb   = (unsigned short*)d_ws;
    unsigned short* w13b = (unsigned short*)((char*)d_ws + XB);
    unsigned short* w2b  = (unsigned short*)((char*)d_ws + XB + W13B);
    __hip_bfloat16* g    = (__hip_bfloat16*)((char*)d_ws + XB + W13B + W2B);
    k_cvt<<<2048, 256, 0, stream>>>(x,   xb,   NX);
    k_cvt<<<2048, 256, 0, stream>>>(w13, w13b, NW13);
    k_cvt<<<2048, 256, 0, stream>>>(w2,  w2b,  NW2);
    k_gateup_f<<<dim3(64, 64), dim3(256), 0, stream>>>(xb, w13b, (__hip_bfloat16*)g);
    k_down_f<<<dim3(24, 64), dim3(256), 0, stream>>>((const unsigned short*)g, w2b, out);
  } else {
    // ---- T2: fp32-source reg-staged GEMMs, g chunked into ws ----
    long mc = (long)(ws_size / (8192 * 2));
    mc -= mc % 128;
    if (mc > 8192) mc = 8192;
    if (mc < 128) mc = 128;  // minimum viable chunk
    for (long m0 = 0; m0 < 8192; m0 += mc) {
      long mrows = 8192 - m0 < mc ? 8192 - m0 : mc;
      __hip_bfloat16* g = (__hip_bfloat16*)d_ws;
      k_gateup_s<<<dim3(64, mrows / 128), dim3(256), 0, stream>>>(
          x + m0 * 3072, w13, g);
      k_down_s<<<dim3(24, mrows / 128), dim3(256), 0, stream>>>(
          (const unsigned short*)g, w2, out + m0 * 3072);
    }
  }
}

// Round 3
// 1199.502 us; speedup vs baseline: 1.0284x; 1.0284x over previous
//
#include <hip/hip_runtime.h>
#include <hip/hip_bf16.h>

// SwiGLU FFN, fp32 in/out: out = clamp(silu(x@w1t) * (x@w3t), ±65504) @ w2t
// x[8192,3072], w13[16384,3072] (rows 0..8191 = w3 -> x3, 8192.. = w1 -> x1), w2[3072,8192].
// bf16 MFMA compute (cvt pre-pass), fp32 accum, fp32 out.
// Round-3 structure: 8-phase-style deep pipeline (T3+T4+T5), 256x128 tiles, 8 waves,
// BK=64, double-buffered LDS, counted vmcnt (never 0 in main loop), raw s_barrier,
// XOR slot-swizzle (pre-swizzled global source + linear gload_lds dest + swizzled ds_read).

typedef __attribute__((ext_vector_type(8))) __bf16 bf16x8;
typedef __attribute__((ext_vector_type(4))) float f32x4;

#define GLD_LDS16(gptr, lptr)                                                        \
  __builtin_amdgcn_global_load_lds(                                                  \
      (const __attribute__((address_space(1))) void*)(gptr),                         \
      (__attribute__((address_space(3))) void*)(lptr), 16, 0, 0)

#define VMCNT(n) asm volatile("s_waitcnt vmcnt(" #n ")" ::: "memory")
#define BAR_SYNC()                                          \
  do {                                                      \
    asm volatile("s_waitcnt lgkmcnt(0)" ::: "memory");      \
    __builtin_amdgcn_s_barrier();                           \
    asm volatile("" ::: "memory");                          \
  } while (0)
#define BAR_ONLY()                                          \
  do {                                                      \
    __builtin_amdgcn_s_barrier();                           \
    asm volatile("" ::: "memory");                          \
  } while (0)

__device__ __forceinline__ __bf16 bfr(float f) {  // RNE fp32->bf16
  unsigned int u = __builtin_bit_cast(unsigned int, f);
  unsigned short r = (unsigned short)((u + 0x7FFFu + ((u >> 16) & 1u)) >> 16);
  return __builtin_bit_cast(__bf16, r);
}

// ---------------- fp32 -> bf16 conversion pre-pass ----------------
__global__ __launch_bounds__(256)
void k_cvt(const float* __restrict__ src, unsigned short* __restrict__ dst, long n) {
  long i = ((long)blockIdx.x * 256 + threadIdx.x) * 8;
  const long stride = (long)gridDim.x * 256 * 8;
  for (; i < n; i += stride) {
    float4 f0 = *(const float4*)(src + i);
    float4 f1 = *(const float4*)(src + i + 4);
    bf16x8 o;
    o[0] = bfr(f0.x); o[1] = bfr(f0.y); o[2] = bfr(f0.z); o[3] = bfr(f0.w);
    o[4] = bfr(f1.x); o[5] = bfr(f1.y); o[6] = bfr(f1.z); o[7] = bfr(f1.w);
    *(bf16x8*)(dst + i) = o;
  }
}

// ============ Kernel 1: fused gate/up, 256x128 tile, 4-phase pipelined ============
// Per tile (BK=64): ph1 Q(mh0) w/ B-nh0; ph2 Q(mh0) w/ B-nh1 (+stage A q0,q2 of t+2);
// ph3 Q(mh1) w/ B-nh0 (+stage B3,B1 of t+2, read A-mh1); ph4 Q(mh1) w/ B-nh1 (+stage A q1,q3).
// 8 gload_lds per tile -> vmcnt(8) at tile entry == all of THIS tile's loads landed.
__global__ __launch_bounds__(512, 2)
void k_gateup8(const unsigned short* __restrict__ X,
               const unsigned short* __restrict__ W13,
               __hip_bfloat16* __restrict__ G)
{
  constexpr int K = 3072, LDG = 8192, NT = K / 64;
  __shared__ unsigned short lds[65536];  // 128 KB: 2 x (A 16384 | B3 8192 | B1 8192)

  const int t = threadIdx.x;
  const int lane = t & 63, wid = t >> 6;
  const int wm = wid >> 2, wn = wid & 3;   // 2M x 4N waves; per-wave out 128x32
  const int l15 = lane & 15, lhi = lane >> 4, sw = l15 & 7;

  const int bid = blockIdx.x;              // 2048 blocks, XCD-chunked swizzle
  const int swz = (bid & 7) * 256 + (bid >> 3);
  const int mb = swz >> 6, nb = swz & 63;

  const int srow = t >> 3;                      // 0..63 (one 64-row quarter per load)
  const int scol = ((t & 7) ^ (srow & 7)) * 8;  // pre-swizzled global slot
  const unsigned short* xa = X   + (size_t)(mb * 256 + srow) * K + scol;
  const unsigned short* b3 = W13 + (size_t)(nb * 128 + srow) * K + scol;
  const unsigned short* b1 = W13 + (size_t)(8192 + nb * 128 + srow) * K + scol;
  const int lo = t * 8;

  f32x4 acc3[8][2], acc1[8][2];
#pragma unroll
  for (int m = 0; m < 8; ++m)
#pragma unroll
    for (int n = 0; n < 2; ++n) {
      acc3[m][n] = (f32x4){0.f, 0.f, 0.f, 0.f};
      acc1[m][n] = (f32x4){0.f, 0.f, 0.f, 0.f};
    }

  // prologue: stage tiles 0 (buf0) and 1 (buf1); 8 loads per tile
#pragma unroll
  for (int tt = 0; tt < 2; ++tt) {
    unsigned short* A  = lds + tt * 32768;
    unsigned short* B3 = A + 16384;
    unsigned short* B1 = A + 24576;
    const int kt = tt * 64;
#pragma unroll
    for (int q = 0; q < 4; ++q)
      GLD_LDS16(xa + (size_t)(q * 64) * K + kt, A + q * 4096 + lo);
#pragma unroll
    for (int r = 0; r < 2; ++r) {
      GLD_LDS16(b3 + (size_t)(r * 64) * K + kt, B3 + r * 4096 + lo);
      GLD_LDS16(b1 + (size_t)(r * 64) * K + kt, B1 + r * 4096 + lo);
    }
  }

  for (int tk = 0; tk < NT; ++tk) {
    unsigned short* A  = lds + (tk & 1) * 32768;
    unsigned short* B3 = A + 16384;
    unsigned short* B1 = A + 24576;
    const int ks = (tk + 2 < NT ? tk + 2 : 0) * 64;  // wrap keeps load-count uniform

    VMCNT(8);     // tile tk's 8 loads landed (tk+1's 8 still in flight)
    BAR_ONLY();

    bf16x8 ra[4][2], r3a[2], r1a[2], r3b[2], r1b[2];
    // ---- ph1: rows mh0, cols nh0 ----
#pragma unroll
    for (int m = 0; m < 4; ++m)
#pragma unroll
      for (int kk = 0; kk < 2; ++kk)
        ra[m][kk] = *(const bf16x8*)(A + (wm * 128 + m * 16 + l15) * 64 + ((kk * 4 + lhi) ^ sw) * 8);
#pragma unroll
    for (int kk = 0; kk < 2; ++kk) {
      r3a[kk] = *(const bf16x8*)(B3 + (wn * 32 + l15) * 64 + ((kk * 4 + lhi) ^ sw) * 8);
      r1a[kk] = *(const bf16x8*)(B1 + (wn * 32 + l15) * 64 + ((kk * 4 + lhi) ^ sw) * 8);
    }
    __builtin_amdgcn_s_setprio(1);
#pragma unroll
    for (int m = 0; m < 4; ++m)
#pragma unroll
      for (int kk = 0; kk < 2; ++kk) {
        acc3[m][0] = __builtin_amdgcn_mfma_f32_16x16x32_bf16(ra[m][kk], r3a[kk], acc3[m][0], 0, 0, 0);
        acc1[m][0] = __builtin_amdgcn_mfma_f32_16x16x32_bf16(ra[m][kk], r1a[kk], acc1[m][0], 0, 0, 0);
      }
    __builtin_amdgcn_s_setprio(0);
    BAR_SYNC();   // A-mh0 (quarters 0,2) fully read by all waves

    // ---- ph2: rows mh0, cols nh1 (+stage A q0,q2 of tile ks) ----
    GLD_LDS16(xa + (size_t)(0 * 64) * K + ks, A + 0 * 4096 + lo);
    GLD_LDS16(xa + (size_t)(2 * 64) * K + ks, A + 2 * 4096 + lo);
#pragma unroll
    for (int kk = 0; kk < 2; ++kk) {
      r3b[kk] = *(const bf16x8*)(B3 + (wn * 32 + 16 + l15) * 64 + ((kk * 4 + lhi) ^ sw) * 8);
      r1b[kk] = *(const bf16x8*)(B1 + (wn * 32 + 16 + l15) * 64 + ((kk * 4 + lhi) ^ sw) * 8);
    }
    __builtin_amdgcn_s_setprio(1);
#pragma unroll
    for (int m = 0; m < 4; ++m)
#pragma unroll
      for (int kk = 0; kk < 2; ++kk) {
        acc3[m][1] = __builtin_amdgcn_mfma_f32_16x16x32_bf16(ra[m][kk], r3b[kk], acc3[m][1], 0, 0, 0);
        acc1[m][1] = __builtin_amdgcn_mfma_f32_16x16x32_bf16(ra[m][kk], r1b[kk], acc1[m][1], 0, 0, 0);
      }
    __builtin_amdgcn_s_setprio(0);
    BAR_SYNC();   // B3/B1 fully read by all waves

    // ---- ph3: rows mh1, cols nh0 (+stage B3,B1 of tile ks; read A-mh1) ----
#pragma unroll
    for (int r = 0; r < 2; ++r) {
      GLD_LDS16(b3 + (size_t)(r * 64) * K + ks, B3 + r * 4096 + lo);
      GLD_LDS16(b1 + (size_t)(r * 64) * K + ks, B1 + r * 4096 + lo);
    }
#pragma unroll
    for (int m = 0; m < 4; ++m)
#pragma unroll
      for (int kk = 0; kk < 2; ++kk)
        ra[m][kk] = *(const bf16x8*)(A + (wm * 128 + 64 + m * 16 + l15) * 64 + ((kk * 4 + lhi) ^ sw) * 8);
    __builtin_amdgcn_s_setprio(1);
#pragma unroll
    for (int m = 0; m < 4; ++m)
#pragma unroll
      for (int kk = 0; kk < 2; ++kk) {
        acc3[4 + m][0] = __builtin_amdgcn_mfma_f32_16x16x32_bf16(ra[m][kk], r3a[kk], acc3[4 + m][0], 0, 0, 0);
        acc1[4 + m][0] = __builtin_amdgcn_mfma_f32_16x16x32_bf16(ra[m][kk], r1a[kk], acc1[4 + m][0], 0, 0, 0);
      }
    __builtin_amdgcn_s_setprio(0);
    BAR_SYNC();   // A-mh1 (quarters 1,3) fully read

    // ---- ph4: rows mh1, cols nh1 (+stage A q1,q3 of tile ks) ----
    GLD_LDS16(xa + (size_t)(1 * 64) * K + ks, A + 1 * 4096 + lo);
    GLD_LDS16(xa + (size_t)(3 * 64) * K + ks, A + 3 * 4096 + lo);
    __builtin_amdgcn_s_setprio(1);
#pragma unroll
    for (int m = 0; m < 4; ++m)
#pragma unroll
      for (int kk = 0; kk < 2; ++kk) {
        acc3[4 + m][1] = __builtin_amdgcn_mfma_f32_16x16x32_bf16(ra[m][kk], r3b[kk], acc3[4 + m][1], 0, 0, 0);
        acc1[4 + m][1] = __builtin_amdgcn_mfma_f32_16x16x32_bf16(ra[m][kk], r1b[kk], acc1[4 + m][1], 0, 0, 0);
      }
    __builtin_amdgcn_s_setprio(0);
    // next iteration opens with VMCNT(8) + barrier
  }

  // epilogue: g = clamp(silu(x1) * x3), bf16 store
  const int gr0 = mb * 256 + wm * 128;
  const int gc0 = nb * 128 + wn * 32;
#pragma unroll
  for (int m = 0; m < 8; ++m)
#pragma unroll
    for (int n = 0; n < 2; ++n)
#pragma unroll
      for (int r = 0; r < 4; ++r) {
        float h3 = acc3[m][n][r];
        float h1 = acc1[m][n][r];
        float s  = h1 / (1.f + __expf(-h1));
        float g  = fminf(fmaxf(s * h3, -65504.f), 65504.f);
        G[(size_t)(gr0 + m * 16 + lhi * 4 + r) * LDG + (gc0 + n * 16 + l15)] =
            __float2bfloat16(g);
      }
}

// ============ Kernel 2: down proj, 256x128 tile, 2-phase pipelined ============
// ph1: read A-mh0(8)+B(8), 16 MFMA; ph2: stage B r0,r1 + A q0,q2 of t+2, read A-mh1,
// 16 MFMA; then stage A q1,q3. 6 loads/tile -> vmcnt(6) at tile entry.
__global__ __launch_bounds__(512, 2)
void k_down8(const unsigned short* __restrict__ Gm,
             const unsigned short* __restrict__ W2,
             float* __restrict__ Out)
{
  constexpr int K = 8192, LDO = 3072, NT = K / 64;
  __shared__ unsigned short lds[49152];  // 96 KB: 2 x (A 16384 | B 8192)

  const int t = threadIdx.x;
  const int lane = t & 63, wid = t >> 6;
  const int wm = wid >> 2, wn = wid & 3;
  const int l15 = lane & 15, lhi = lane >> 4, sw = l15 & 7;

  const int bid = blockIdx.x;              // 768 blocks
  const int swz = (bid & 7) * 96 + (bid >> 3);
  const int mb = swz / 24, nb = swz % 24;

  const int srow = t >> 3;
  const int scol = ((t & 7) ^ (srow & 7)) * 8;
  const unsigned short* ga = Gm + (size_t)(mb * 256 + srow) * K + scol;
  const unsigned short* wb = W2 + (size_t)(nb * 128 + srow) * K + scol;
  const int lo = t * 8;

  f32x4 acc[8][2];
#pragma unroll
  for (int m = 0; m < 8; ++m)
#pragma unroll
    for (int n = 0; n < 2; ++n)
      acc[m][n] = (f32x4){0.f, 0.f, 0.f, 0.f};

  // prologue: tiles 0,1 (6 loads each)
#pragma unroll
  for (int tt = 0; tt < 2; ++tt) {
    unsigned short* A = lds + tt * 24576;
    unsigned short* B = A + 16384;
    const int kt = tt * 64;
#pragma unroll
    for (int q = 0; q < 4; ++q)
      GLD_LDS16(ga + (size_t)(q * 64) * K + kt, A + q * 4096 + lo);
#pragma unroll
    for (int r = 0; r < 2; ++r)
      GLD_LDS16(wb + (size_t)(r * 64) * K + kt, B + r * 4096 + lo);
  }

  for (int tk = 0; tk < NT; ++tk) {
    unsigned short* A = lds + (tk & 1) * 24576;
    unsigned short* B = A + 16384;
    const int ks = (tk + 2 < NT ? tk + 2 : 0) * 64;

    VMCNT(6);
    BAR_ONLY();

    bf16x8 ra[4][2], rb[2][2];
    // ---- ph1: rows mh0, all cols ----
#pragma unroll
    for (int m = 0; m < 4; ++m)
#pragma unroll
      for (int kk = 0; kk < 2; ++kk)
        ra[m][kk] = *(const bf16x8*)(A + (wm * 128 + m * 16 + l15) * 64 + ((kk * 4 + lhi) ^ sw) * 8);
#pragma unroll
    for (int n = 0; n < 2; ++n)
#pragma unroll
      for (int kk = 0; kk < 2; ++kk)
        rb[n][kk] = *(const bf16x8*)(B + (wn * 32 + n * 16 + l15) * 64 + ((kk * 4 + lhi) ^ sw) * 8);
    __builtin_amdgcn_s_setprio(1);
#pragma unroll
    for (int m = 0; m < 4; ++m)
#pragma unroll
      for (int n = 0; n < 2; ++n)
#pragma unroll
        for (int kk = 0; kk < 2; ++kk)
          acc[m][n] = __builtin_amdgcn_mfma_f32_16x16x32_bf16(ra[m][kk], rb[n][kk], acc[m][n], 0, 0, 0);
    __builtin_amdgcn_s_setprio(0);
    BAR_SYNC();   // B + A quarters 0,2 fully read

    // ---- ph2: stage B r0,r1 + A q0,q2 of tile ks; rows mh1 ----
#pragma unroll
    for (int r = 0; r < 2; ++r)
      GLD_LDS16(wb + (size_t)(r * 64) * K + ks, B + r * 4096 + lo);
    GLD_LDS16(ga + (size_t)(0 * 64) * K + ks, A + 0 * 4096 + lo);
    GLD_LDS16(ga + (size_t)(2 * 64) * K + ks, A + 2 * 4096 + lo);
#pragma unroll
    for (int m = 0; m < 4; ++m)
#pragma unroll
      for (int kk = 0; kk < 2; ++kk)
        ra[m][kk] = *(const bf16x8*)(A + (wm * 128 + 64 + m * 16 + l15) * 64 + ((kk * 4 + lhi) ^ sw) * 8);
    __builtin_amdgcn_s_setprio(1);
#pragma unroll
    for (int m = 0; m < 4; ++m)
#pragma unroll
      for (int n = 0; n < 2; ++n)
#pragma unroll
        for (int kk = 0; kk < 2; ++kk)
          acc[4 + m][n] = __builtin_amdgcn_mfma_f32_16x16x32_bf16(ra[m][kk], rb[n][kk], acc[4 + m][n], 0, 0, 0);
    __builtin_amdgcn_s_setprio(0);
    BAR_SYNC();   // A quarters 1,3 fully read
    GLD_LDS16(ga + (size_t)(1 * 64) * K + ks, A + 1 * 4096 + lo);
    GLD_LDS16(ga + (size_t)(3 * 64) * K + ks, A + 3 * 4096 + lo);
    // next iteration opens with VMCNT(6) + barrier
  }

  const int r0 = mb * 256 + wm * 128;
  const int c0 = nb * 128 + wn * 32;
#pragma unroll
  for (int m = 0; m < 8; ++m)
#pragma unroll
    for (int n = 0; n < 2; ++n)
#pragma unroll
      for (int r = 0; r < 4; ++r)
        Out[(size_t)(r0 + m * 16 + lhi * 4 + r) * LDO + (c0 + n * 16 + l15)] =
            acc[m][n][r];
}

extern "C" void kernel_launch(void* const* d_in, const int* in_sizes, int n_in,
                              void* d_out, int out_size, void* d_ws, size_t ws_size,
                              hipStream_t stream) {
  const float* x   = (const float*)d_in[0];   // [2,4096,3072] f32
  const float* w13 = (const float*)d_in[1];   // [16384,3072] f32
  const float* w2  = (const float*)d_in[2];   // [3072,8192] f32
  float* out = (float*)d_out;                 // [2,4096,3072] f32

  const long NX = 25165824L, NW13 = 50331648L, NW2 = 25165824L;
  const size_t XB = 50331648, W13B = 100663296, W2B = 50331648;

  unsigned short* xb   = (unsigned short*)d_ws;
  unsigned short* w13b = (unsigned short*)((char*)d_ws + XB);
  unsigned short* w2b  = (unsigned short*)((char*)d_ws + XB + W13B);
  __hip_bfloat16* g    = (__hip_bfloat16*)((char*)d_ws + XB + W13B + W2B);

  k_cvt<<<2048, 256, 0, stream>>>(x,   xb,   NX);
  k_cvt<<<2048, 256, 0, stream>>>(w13, w13b, NW13);
  k_cvt<<<2048, 256, 0, stream>>>(w2,  w2b,  NW2);
  k_gateup8<<<2048, 512, 0, stream>>>(xb, w13b, g);
  k_down8<<<768, 512, 0, stream>>>((const unsigned short*)g, w2b, out);
}